// Round 15
// baseline (73.589 us; speedup 1.0000x reference)
//
#include <hip/hip_runtime.h>
#include <stdint.h>

typedef __attribute__((ext_vector_type(4))) int int4v;
typedef __attribute__((ext_vector_type(4))) float float4v;

#define NB 96
#define SS 1024
#define DD 64
#define TILE_U32 2048        // 8 KB packed B image per 128-col tile

// psi: bit-swapped nibble for bank-conflict-free fragment reads
__device__ __forceinline__ int PSI(int r) { return ((r & 3) << 2) | (r >> 2); }

// Pack byte0 of four int32s (each holding an int8 value) into one dword.
static __device__ __forceinline__ uint32_t pack4(uint32_t a, uint32_t b,
                                                 uint32_t c, uint32_t d) {
    uint32_t lo = __builtin_amdgcn_perm(b, a, 0x00000400u);  // [a0,b0,x,x]
    uint32_t hi = __builtin_amdgcn_perm(d, c, 0x00000400u);  // [c0,d0,x,x]
    return __builtin_amdgcn_perm(hi, lo, 0x05040100u);       // [a0,b0,c0,d0]
}

// out[b][s][t] = alpha * ( C - bz*rowsum(x) - az*colsum(y) + 64*az*bz )
// exact int32 via mfma_i32_16x16x64_i8.
// Grid 6144 = 96 x 8nt x 8mt: each block packs its (b,nt) B-tile into LDS
// (8x redundant globally; Y is L2/L3-resident) and computes ONE mt tile.
// Direct nt stores, 4 rows x 256 B per instruction.
__global__ __launch_bounds__(256) void bmm_i8zp_kernel(
    const int* __restrict__ X,   // raw [96][1024][64] int32 (int8 values)
    const int* __restrict__ Y,   // raw [96][64][1024] int32
    const float* __restrict__ azp,
    const float* __restrict__ bzp,
    const float* __restrict__ alp,
    float* __restrict__ out)     // [96][1024][1024] fp32
{
    __shared__ uint32_t sb[TILE_U32];   // packed+permuted B image (8 KB)

    const int tid = threadIdx.x;
    // XCD swizzle: grid 6144 = 8 XCDs x 768; each XCD owns 12 whole batches
    const int bid = (blockIdx.x & 7) * 768 + (blockIdx.x >> 3);
    const int b   = bid >> 6;
    const int nt  = (bid >> 3) & 7;
    const int mt  = bid & 7;
    const int colbase = nt * 128;
    const int rowbase = mt * 128;

    const float az = *azp, bz = *bzp, al = *alp;
    const float czk = az * bz * (float)DD;

    // ---- stage + transpose + permute B panel (64 k x 128 t) into LDS ----
    // image row u holds logical col sigma(u) = (u>>6)*64 + 4*(u&15) + ((u>>4)&3),
    // intra-row dword slot kw ^ PSI(u&15) -> lane's 4 accs = 4 consecutive cols
    {
        const int* Yb = Y + (size_t)b * (DD * SS) + colbase;
        const int tw = tid & 31;            // logical col quad (cols 4tw..4tw+3)
        const int r  = tw & 15, wnp = tw >> 4;
        const int4v* srcBase = (const int4v*)Yb + tw;
        #pragma unroll
        for (int it = 0; it < 2; ++it) {
            const int kw = (tid >> 5) + 8 * it;
            const int4v* src = srcBase + (size_t)(4 * kw) * (SS / 4);
            int4v r0 = src[0];
            int4v r1 = src[SS / 4];
            int4v r2 = src[2 * (SS / 4)];
            int4v r3 = src[3 * (SS / 4)];
            const int slot = kw ^ PSI(r);
            #pragma unroll
            for (int n = 0; n < 4; ++n) {
                uint32_t pk = pack4((uint32_t)r0[n], (uint32_t)r1[n],
                                    (uint32_t)r2[n], (uint32_t)r3[n]);
                sb[(wnp * 64 + n * 16 + r) * 16 + slot] = pk;
            }
        }
    }
    __syncthreads();

    const int wid  = tid >> 6;      // 4 waves, 2x2 over the 128x128 tile
    const int lane = tid & 63;
    const int wm = wid >> 1, wn = wid & 1;
    const int rr = lane & 15, qq = lane >> 4;

    // B fragments: slot rr of bF[n] = logical col 4rr+n
    int4v bF[4];
    #pragma unroll
    for (int n = 0; n < 4; ++n) {
        const int u = wn * 64 + n * 16 + rr;
        int4v v;
        #pragma unroll
        for (int c = 0; c < 4; ++c)
            v[c] = (int)sb[u * 16 + ((qq * 4 + c) ^ PSI(rr))];
        bF[n] = v;
    }

    const int4v ones = {0x01010101, 0x01010101, 0x01010101, 0x01010101};
    const int4v zero = {0, 0, 0, 0};

    // colsum correction (exact integer-valued): az*colsum_y[col 4rr+n]
    float cyI[4];
    #pragma unroll
    for (int n = 0; n < 4; ++n) {
        int4v cy = __builtin_amdgcn_mfma_i32_16x16x64_i8(ones, bF[n], zero, 0, 0, 0);
        cyI[n] = az * (float)cy[0];
    }

    float* outb = out + (size_t)b * SS * SS;
    const int cb = colbase + wn * 64 + 4 * rr;
    const int* Xw = X + ((size_t)(b * SS + rowbase + wm * 64 + rr)) * DD + qq * 16;

    #pragma unroll
    for (int m = 0; m < 4; ++m) {
        // A fragment: 16 consecutive rows x 256 B, coalesced; pack in-reg
        const int4v* arow = (const int4v*)(Xw + (size_t)(m * 16) * DD);
        int4v w0 = arow[0], w1 = arow[1], w2 = arow[2], w3 = arow[3];
        int4v aF;
        aF[0] = (int)pack4((uint32_t)w0[0], (uint32_t)w0[1], (uint32_t)w0[2], (uint32_t)w0[3]);
        aF[1] = (int)pack4((uint32_t)w1[0], (uint32_t)w1[1], (uint32_t)w1[2], (uint32_t)w1[3]);
        aF[2] = (int)pack4((uint32_t)w2[0], (uint32_t)w2[1], (uint32_t)w2[2], (uint32_t)w2[3]);
        aF[3] = (int)pack4((uint32_t)w3[0], (uint32_t)w3[1], (uint32_t)w3[2], (uint32_t)w3[3]);

        int4v rx = __builtin_amdgcn_mfma_i32_16x16x64_i8(aF, ones, zero, 0, 0, 0);
        int4v acc[4];
        #pragma unroll
        for (int n = 0; n < 4; ++n)
            acc[n] = __builtin_amdgcn_mfma_i32_16x16x64_i8(aF, bF[n], zero, 0, 0, 0);

        const int rb = rowbase + wm * 64 + m * 16 + qq * 4;
        #pragma unroll
        for (int j = 0; j < 4; ++j) {
            const float corr = czk - bz * (float)rx[j];   // exact int
            float4v v;
            #pragma unroll
            for (int n = 0; n < 4; ++n)
                v[n] = ((float)acc[n][j] - cyI[n] + corr) * al;  // exact bracket
            __builtin_nontemporal_store(
                v, (float4v*)(outb + (size_t)(rb + j) * SS + cb));
        }
    }
}

extern "C" void kernel_launch(void* const* d_in, const int* in_sizes, int n_in,
                              void* d_out, int out_size, void* d_ws, size_t ws_size,
                              hipStream_t stream)
{
    const int* X = (const int*)d_in[0];
    const int* Y = (const int*)d_in[1];
    const float* azp = (const float*)d_in[2];
    const float* bzp = (const float*)d_in[3];
    const float* alp = (const float*)d_in[4];
    float* out = (float*)d_out;

    hipLaunchKernelGGL(bmm_i8zp_kernel, dim3(NB * 8 * 8), dim3(256), 0, stream,
                       X, Y, azp, bzp, alp, out);
}

// Round 16
// 72.470 us; speedup vs baseline: 1.0154x; 1.0154x over previous
//
#include <hip/hip_runtime.h>
#include <stdint.h>

typedef __attribute__((ext_vector_type(4))) int int4v;
typedef __attribute__((ext_vector_type(4))) float float4v;

#define NB 96
#define SS 1024
#define DD 64
#define TILE_U32 2048        // 8 KB packed B image per 128-col tile

// psi: bit-swapped nibble for bank-conflict-free fragment reads
__device__ __forceinline__ int PSI(int r) { return ((r & 3) << 2) | (r >> 2); }

// Pack byte0 of four int32s (each holding an int8 value) into one dword.
static __device__ __forceinline__ uint32_t pack4(uint32_t a, uint32_t b,
                                                 uint32_t c, uint32_t d) {
    uint32_t lo = __builtin_amdgcn_perm(b, a, 0x00000400u);  // [a0,b0,x,x]
    uint32_t hi = __builtin_amdgcn_perm(d, c, 0x00000400u);  // [c0,d0,x,x]
    return __builtin_amdgcn_perm(hi, lo, 0x05040100u);       // [a0,b0,c0,d0]
}

// out[b][s][t] = alpha * ( C - bz*rowsum(x) - az*colsum(y) + 64*az*bz )
// exact int32 via mfma_i32_16x16x64_i8.
// Grid 3072 = 96 x 8nt x 4 row-groups: each block packs its (b,nt) B-tile
// into LDS (4x redundant globally, but Y is L2/L3-resident) and computes
// 2 mt output tiles. Direct nt stores, 4 rows x 256 B per instruction.
__global__ __launch_bounds__(256) void bmm_i8zp_kernel(
    const int* __restrict__ X,   // raw [96][1024][64] int32 (int8 values)
    const int* __restrict__ Y,   // raw [96][64][1024] int32
    const float* __restrict__ azp,
    const float* __restrict__ bzp,
    const float* __restrict__ alp,
    float* __restrict__ out)     // [96][1024][1024] fp32
{
    __shared__ uint32_t sb[TILE_U32];   // packed+permuted B image (8 KB)

    const int tid = threadIdx.x;
    // XCD swizzle: grid 3072 = 8 XCDs x 384; each XCD owns 12 whole batches
    const int bid = (blockIdx.x & 7) * 384 + (blockIdx.x >> 3);
    const int b   = bid >> 5;
    const int nt  = (bid >> 2) & 7;
    const int mg  = bid & 3;            // row-group: mt = mg*2 + {0,1}
    const int colbase = nt * 128;

    const float az = *azp, bz = *bzp, al = *alp;
    const float czk = az * bz * (float)DD;

    // ---- stage + transpose + permute B panel (64 k x 128 t) into LDS ----
    // image row u holds logical col sigma(u) = (u>>6)*64 + 4*(u&15) + ((u>>4)&3),
    // intra-row dword slot kw ^ PSI(u&15) -> lane's 4 accs = 4 consecutive cols
    {
        const int* Yb = Y + (size_t)b * (DD * SS) + colbase;
        const int tw = tid & 31;            // logical col quad (cols 4tw..4tw+3)
        const int r  = tw & 15, wnp = tw >> 4;
        const int4v* srcBase = (const int4v*)Yb + tw;
        #pragma unroll
        for (int it = 0; it < 2; ++it) {
            const int kw = (tid >> 5) + 8 * it;
            const int4v* src = srcBase + (size_t)(4 * kw) * (SS / 4);
            int4v r0 = src[0];
            int4v r1 = src[SS / 4];
            int4v r2 = src[2 * (SS / 4)];
            int4v r3 = src[3 * (SS / 4)];
            const int slot = kw ^ PSI(r);
            #pragma unroll
            for (int n = 0; n < 4; ++n) {
                uint32_t pk = pack4((uint32_t)r0[n], (uint32_t)r1[n],
                                    (uint32_t)r2[n], (uint32_t)r3[n]);
                sb[(wnp * 64 + n * 16 + r) * 16 + slot] = pk;
            }
        }
    }
    __syncthreads();

    const int wid  = tid >> 6;      // 4 waves, 2x2 over each 128x128 tile
    const int lane = tid & 63;
    const int wm = wid >> 1, wn = wid & 1;
    const int rr = lane & 15, qq = lane >> 4;

    // B fragments (persistent): slot rr of bF[n] = logical col 4rr+n
    int4v bF[4];
    #pragma unroll
    for (int n = 0; n < 4; ++n) {
        const int u = wn * 64 + n * 16 + rr;
        int4v v;
        #pragma unroll
        for (int c = 0; c < 4; ++c)
            v[c] = (int)sb[u * 16 + ((qq * 4 + c) ^ PSI(rr))];
        bF[n] = v;
    }

    const int4v ones = {0x01010101, 0x01010101, 0x01010101, 0x01010101};
    const int4v zero = {0, 0, 0, 0};

    // colsum correction (exact integer-valued): az*colsum_y[col 4rr+n]
    float cyI[4];
    #pragma unroll
    for (int n = 0; n < 4; ++n) {
        int4v cy = __builtin_amdgcn_mfma_i32_16x16x64_i8(ones, bF[n], zero, 0, 0, 0);
        cyI[n] = az * (float)cy[0];
    }

    float* outb = out + (size_t)b * SS * SS;
    const int cb = colbase + wn * 64 + 4 * rr;
    const int* Xw = X + ((size_t)b * SS + wm * 64 + rr) * DD + qq * 16;

    #pragma unroll
    for (int mi = 0; mi < 2; ++mi) {
        const int rowbase = (mg * 2 + mi) * 128;
        #pragma unroll
        for (int m = 0; m < 4; ++m) {
            // A fragment: 16 consecutive rows x 256 B, coalesced; pack in-reg
            const int4v* arow = (const int4v*)(Xw + (size_t)(rowbase + m * 16) * DD);
            int4v w0 = arow[0], w1 = arow[1], w2 = arow[2], w3 = arow[3];
            int4v aF;
            aF[0] = (int)pack4((uint32_t)w0[0], (uint32_t)w0[1], (uint32_t)w0[2], (uint32_t)w0[3]);
            aF[1] = (int)pack4((uint32_t)w1[0], (uint32_t)w1[1], (uint32_t)w1[2], (uint32_t)w1[3]);
            aF[2] = (int)pack4((uint32_t)w2[0], (uint32_t)w2[1], (uint32_t)w2[2], (uint32_t)w2[3]);
            aF[3] = (int)pack4((uint32_t)w3[0], (uint32_t)w3[1], (uint32_t)w3[2], (uint32_t)w3[3]);

            int4v rx = __builtin_amdgcn_mfma_i32_16x16x64_i8(aF, ones, zero, 0, 0, 0);
            int4v acc[4];
            #pragma unroll
            for (int n = 0; n < 4; ++n)
                acc[n] = __builtin_amdgcn_mfma_i32_16x16x64_i8(aF, bF[n], zero, 0, 0, 0);

            const int rb = rowbase + wm * 64 + m * 16 + qq * 4;
            #pragma unroll
            for (int j = 0; j < 4; ++j) {
                const float corr = czk - bz * (float)rx[j];   // exact int
                float4v v;
                #pragma unroll
                for (int n = 0; n < 4; ++n)
                    v[n] = ((float)acc[n][j] - cyI[n] + corr) * al;  // exact bracket
                __builtin_nontemporal_store(
                    v, (float4v*)(outb + (size_t)(rb + j) * SS + cb));
            }
        }
    }
}

extern "C" void kernel_launch(void* const* d_in, const int* in_sizes, int n_in,
                              void* d_out, int out_size, void* d_ws, size_t ws_size,
                              hipStream_t stream)
{
    const int* X = (const int*)d_in[0];
    const int* Y = (const int*)d_in[1];
    const float* azp = (const float*)d_in[2];
    const float* bzp = (const float*)d_in[3];
    const float* alp = (const float*)d_in[4];
    float* out = (float*)d_out;

    hipLaunchKernelGGL(bmm_i8zp_kernel, dim3(NB * 8 * 4), dim3(256), 0, stream,
                       X, Y, azp, bzp, alp, out);
}